// Round 3
// baseline (541.077 us; speedup 1.0000x reference)
//
#include <hip/hip_runtime.h>

// Side Window Filter — bit-exact vs harness np ref (absmax 0.0 contract).
// Math contract (DO NOT REORDER): per output, each of the 8 windows is a
// sequential __builtin_fmaf chain over its taps in row-major (i,j) order,
// fp32 accumulator starting at 0, weights fp32(1/15), fp32(1/9); replicate
// boundary; 8 iterations; fp32 iterates; fp32 d/argmin(first-idx)/update;
// final clip(|x0-res|,0,255).
//
// R13: same LDS-halo scheme as R12 (replicate clamp folded into halo
// values; no divergent edge path in compute) but restructured for TLP:
// 1-wave workgroups (64 thr), 256-float column strip, RPT=4 output rows.
// LDS = 8 rows x 276 floats = 8.8 KB -> 18 resident blocks/CU and the
// grid is 12288 blocks (48 generations/CU), so staging latency and the
// (single-wave, nearly free) barrier hide under 18-deep block interleave.
// R12's failure mode was 6 resident blocks x 2 generations = no overlap.

static constexpr int H     = 2048;
static constexpr int W     = 2048;
static constexpr int C     = 3;
static constexpr int WC    = W * C;        // 6144 floats per row
static constexpr int RPT   = 4;            // output rows per block
static constexpr int TPB   = 64;           // one wave per block
static constexpr int BCOLS = TPB * 4;      // 256 output floats per block
static constexpr int RW    = BCOLS + 20;   // 276 staged floats per row
static constexpr int NROWS = RPT + 4;      // 8 staged rows
static constexpr int NCH   = RW / 4;       // 69 float4 chunks per row
static constexpr int NBX   = WC / BCOLS;   // 24 x-blocks

template<bool FINAL>
__global__ __launch_bounds__(TPB)
void swf_lds(const float* __restrict__ src, float* __restrict__ dst,
             const float* __restrict__ x0) {
  __shared__ __align__(16) float s[NROWS][RW];

  const int tid  = threadIdx.x;
  const int bx   = blockIdx.x;
  const int y0   = blockIdx.y * RPT;
  const int base = bx * BCOLS - 8;       // global float idx of LDS col 0

  // interior iff every staged float of this block is in [0, WC)
  const bool interior = (bx >= 1) && (bx <= NBX - 2);

  // ---- stage 8 rows (vertical replicate via hy clamp; horizontal
  //      replicate folded into halo values) ----
#pragma unroll 1
  for (int r = 0; r < NROWS; ++r) {
    int hy = y0 + r - 2;
    hy = hy < 0 ? 0 : (hy > H - 1 ? H - 1 : hy);
    const float* srow = src + (size_t)hy * WC;
    if (interior) {
      // chunk A: cc = tid; chunk B: cc = tid + 64 (5 active lanes)
      const float4 va = *(const float4*)(srow + base + tid * 4);
      *(float4*)&s[r][tid * 4] = va;
      if (tid < NCH - 64) {
        const float4 vb = *(const float4*)(srow + base + (tid + 64) * 4);
        *(float4*)&s[r][(tid + 64) * 4] = vb;
      }
    } else {
#pragma unroll 1
      for (int cc = tid; cc < NCH; cc += TPB) {
        const int gp = base + cc * 4;
        float tmp[4];
#pragma unroll
        for (int u = 0; u < 4; ++u) {
          const int f = gp + u;
          const int idx = (f < 0)    ? ((f % 3) + 3) % 3
                        : (f >= WC)  ? (W - 1) * 3 + (f % 3)
                        : f;
          tmp[u] = srow[idx];
        }
        float4 v; v.x = tmp[0]; v.y = tmp[1]; v.z = tmp[2]; v.w = tmp[3];
        *(float4*)&s[r][cc * 4] = v;
      }
    }
  }
  __syncthreads();

  const float w15 = 1.0f / 15.0f;   // fp32(1/15)
  const float w9  = 1.0f / 9.0f;    // fp32(1/9)
  const int   lc   = tid * 4;               // LDS float idx of window start
  const int   col4 = bx * BCOLS + tid * 4;  // global output float idx

#pragma unroll 1
  for (int t = 0; t < RPT; ++t) {
    float acc[4][8];
#pragma unroll
    for (int k = 0; k < 4; ++k)
#pragma unroll
      for (int m = 0; m < 8; ++m) acc[k][m] = 0.0f;
    float center[4];

#pragma unroll
    for (int i = 0; i < 5; ++i) {
      const float* row = &s[t + i][lc];
      const float4 q0 = *(const float4*)(row);
      const float4 q1 = *(const float4*)(row + 4);
      const float4 q2 = *(const float4*)(row + 8);
      const float4 q3 = *(const float4*)(row + 12);
      const float4 q4 = *(const float4*)(row + 16);
      const float r[20] = {q0.x,q0.y,q0.z,q0.w, q1.x,q1.y,q1.z,q1.w,
                           q2.x,q2.y,q2.z,q2.w, q3.x,q3.y,q3.z,q3.w,
                           q4.x,q4.y,q4.z,q4.w};
#pragma unroll
      for (int k = 0; k < 4; ++k) {
        // tap j of output col4+k -> r[k + 3j + 2]
        const float t0 = r[k+2], t1 = r[k+5], t2 = r[k+8],
                    t3 = r[k+11], t4 = r[k+14];
        float* a = acc[k];
        if (i == 2) center[k] = t2;
        // L: cols 0..2, all rows
        a[0]=__builtin_fmaf(w15,t0,a[0]); a[0]=__builtin_fmaf(w15,t1,a[0]); a[0]=__builtin_fmaf(w15,t2,a[0]);
        // R: cols 2..4, all rows
        a[1]=__builtin_fmaf(w15,t2,a[1]); a[1]=__builtin_fmaf(w15,t3,a[1]); a[1]=__builtin_fmaf(w15,t4,a[1]);
        if (i <= 2) {  // U: rows 0..2, all cols
          a[2]=__builtin_fmaf(w15,t0,a[2]); a[2]=__builtin_fmaf(w15,t1,a[2]); a[2]=__builtin_fmaf(w15,t2,a[2]);
          a[2]=__builtin_fmaf(w15,t3,a[2]); a[2]=__builtin_fmaf(w15,t4,a[2]);
          // NW / NE
          a[4]=__builtin_fmaf(w9,t0,a[4]); a[4]=__builtin_fmaf(w9,t1,a[4]); a[4]=__builtin_fmaf(w9,t2,a[4]);
          a[5]=__builtin_fmaf(w9,t2,a[5]); a[5]=__builtin_fmaf(w9,t3,a[5]); a[5]=__builtin_fmaf(w9,t4,a[5]);
        }
        if (i >= 2) {  // D: rows 2..4, all cols
          a[3]=__builtin_fmaf(w15,t0,a[3]); a[3]=__builtin_fmaf(w15,t1,a[3]); a[3]=__builtin_fmaf(w15,t2,a[3]);
          a[3]=__builtin_fmaf(w15,t3,a[3]); a[3]=__builtin_fmaf(w15,t4,a[3]);
          // SW / SE
          a[6]=__builtin_fmaf(w9,t0,a[6]); a[6]=__builtin_fmaf(w9,t1,a[6]); a[6]=__builtin_fmaf(w9,t2,a[6]);
          a[7]=__builtin_fmaf(w9,t2,a[7]); a[7]=__builtin_fmaf(w9,t3,a[7]); a[7]=__builtin_fmaf(w9,t4,a[7]);
        }
      }
    }

    // epilogue for output row y0+t: fp32 d/argmin/update, float4 store
    const int y = y0 + t;
    float4 xv4;
    if (FINAL) xv4 = *(const float4*)(x0 + (size_t)y * WC + col4);
    float o[4];
#pragma unroll
    for (int k = 0; k < 4; ++k) {
      float best  = acc[k][0] - center[k];
      float besta = fabsf(best);
#pragma unroll
      for (int m = 1; m < 8; ++m) {
        const float d = acc[k][m] - center[k];
        const float a = fabsf(d);
        if (a < besta) { besta = a; best = d; }
      }
      const float res = center[k] + best;
      if (FINAL) {
        const float xv = (k == 0) ? xv4.x : (k == 1) ? xv4.y
                       : (k == 2) ? xv4.z : xv4.w;
        float diff = fabsf(xv - res);
        o[k] = diff > 255.0f ? 255.0f : diff;
      } else {
        o[k] = res;
      }
    }
    float4 ov;
    ov.x = o[0]; ov.y = o[1]; ov.z = o[2]; ov.w = o[3];
    *(float4*)(dst + (size_t)y * WC + col4) = ov;
  }
}

extern "C" void kernel_launch(void* const* d_in, const int* in_sizes, int n_in,
                              void* d_out, int out_size, void* d_ws, size_t ws_size,
                              hipStream_t stream) {
  const float* x0  = (const float*)d_in[0];
  float*       out = (float*)d_out;
  float*       ws  = (float*)d_ws;   // needs H*W*C*4 = 50.3 MB

  dim3 grid(NBX, H / RPT);           // 24 x-blocks, 512 y-blocks
  dim3 block(TPB);

  swf_lds<false><<<grid, block, 0, stream>>>(x0,  ws,  nullptr);  // iter 1
  swf_lds<false><<<grid, block, 0, stream>>>(ws,  out, nullptr);  // iter 2
  swf_lds<false><<<grid, block, 0, stream>>>(out, ws,  nullptr);  // iter 3
  swf_lds<false><<<grid, block, 0, stream>>>(ws,  out, nullptr);  // iter 4
  swf_lds<false><<<grid, block, 0, stream>>>(out, ws,  nullptr);  // iter 5
  swf_lds<false><<<grid, block, 0, stream>>>(ws,  out, nullptr);  // iter 6
  swf_lds<false><<<grid, block, 0, stream>>>(out, ws,  nullptr);  // iter 7
  swf_lds<true ><<<grid, block, 0, stream>>>(ws,  out, x0);       // iter 8 + diff
}